// Round 14
// baseline (8105.871 us; speedup 1.0000x reference)
//
#include <hip/hip_runtime.h>

#define NIN  512
#define NREC 2048
#define NOUT 128
#define BB   64
#define TT   250
#define NQ   8      // column slices (one per XCD under gid%8 round-robin)
#define SC   256    // columns per slice

// OUTPUTS FLOAT32 (R9). Semantics: JAX text (R10+ PASS, absmax 0.0078125).
// ---- d_ws layout (~31.4 MB; 34.5 MB verified safe) ----
#define OFF_WQ   0UL          // f32 [q][n][c] per-slice W_r^T   16,777,216
#define OFF_DQ   16777216UL   // u8  [q][n][c] per-slice delays   4,194,304
#define OFF_IQ   20971520UL   // f32 [q][i][c] per-slice W_i^T    4,194,304
#define OFF_WOT  25165824UL   // f32 [n][o] W_o^T                 1,048,576
#define OFF_MASK 26214400UL   // u32 masks [t*64+b][64]           4,096,000
#define OFF_G    30310400UL   // f64 g[b][n]                      1,048,576
#define OFF_CNT  31358976UL   // u32 cnt[t*64+b]                     64,000 (memset 0)

__device__ __forceinline__ int decode_delay(int v) {
    if (v >= 0 && v <= 4) return v;
    const float f = __int_as_float(v);
    if (f >= 0.5f && f <= 4.5f) return (int)(f + 0.5f);
    return 0;
}
__device__ __forceinline__ int delay_like(int v) {
    if (v >= 0 && v <= 4) return 1;
    const float f = __int_as_float(v);
    return (f >= 0.5f && f <= 4.5f) ? 1 : 0;
}
__device__ __forceinline__ unsigned lane_rank(unsigned long long m) {
    unsigned r = __builtin_amdgcn_mbcnt_lo((unsigned)m, 0u);
    return __builtin_amdgcn_mbcnt_hi((unsigned)(m >> 32), r);
}

// Stage per-slice packed weights/delays (sniffs delays vs W_r input pair).
__global__ __launch_bounds__(256) void k_prep(
    const void* __restrict__ c4A, const void* __restrict__ c4B,
    const float* __restrict__ Wi, const float* __restrict__ Wo,
    float* __restrict__ Wq, unsigned char* __restrict__ Dq,
    float* __restrict__ Iq, float* __restrict__ WoT)
{
    const int* iA = (const int*)c4A;
    const int* iB = (const int*)c4B;
    int cntA = 0, cntB = 0;
    for (int j = 0; j < 64; ++j) { cntA += delay_like(iA[j]); cntB += delay_like(iB[j]); }
    const int*   dl = (cntA >= cntB) ? iA : iB;
    const float* Wr = (cntA >= cntB) ? (const float*)c4B : (const float*)c4A;

    const int idx = blockIdx.x * 256 + threadIdx.x;
    if (idx < NREC * NREC) {
        const int n = idx >> 11, m = idx & 2047;
        const int q = m >> 8, c = m & 255;
        const size_t dst = ((size_t)(q * NREC + n) << 8) + c;
        Wq[dst] = Wr[(size_t)m * NREC + n];              // W_r[m][n]
        Dq[dst] = (unsigned char)decode_delay(dl[idx]);  // delays[n][m]
    }
    if (idx < NIN * NREC) {
        const int i = idx >> 11, m = idx & 2047;
        const int q = m >> 8, c = m & 255;
        Iq[((size_t)(q * NIN + i) << 8) + c] = Wi[(size_t)m * NIN + i];   // W_i[m][i]
    }
    if (idx < NREC * NOUT) {
        const int n = idx >> 7, o = idx & 127;
        WoT[idx] = Wo[(size_t)o * NREC + n];
    }
}

// R14: 512 blocks x 256 threads. Block (b,q) owns neuron cols [256q,256q+256)
// of batch b; q = gid&7 aligns slice q with XCD q (round-robin heuristic) so
// each XCD's 2.5 MB slice is L2-resident. 8-sibling per-step spike exchange
// via spikeMask + release/acquire counter (R13-verified pattern). 2 blocks/CU.
__global__ __launch_bounds__(256) void k_main(
    const float* __restrict__ x,
    const float* __restrict__ Wq, const unsigned char* __restrict__ Dq,
    const float* __restrict__ Iq,
    const float* __restrict__ Br,
    const float* __restrict__ tau_rec, const float* __restrict__ tau_out,
    const float* __restrict__ thr_rec,
    unsigned* __restrict__ spikeMask, unsigned* __restrict__ cnt,
    double* __restrict__ g)
{
    __shared__ int icnt[8];
    __shared__ unsigned short ilist[NIN];
    __shared__ unsigned words[64];
    __shared__ int zcnt[64];
    __shared__ int zoff[64];
    __shared__ unsigned short slist[NREC];

    const int gid = blockIdx.x;
    const int q   = gid & 7;           // slice == XCD (heuristic; correctness-independent)
    const int b   = gid >> 3;
    const int tid  = threadIdx.x;
    const int w    = tid >> 6;         // wave 0..3
    const int lane = tid & 63;

    const float*         Wqq = Wq + ((size_t)q * NREC << 8);
    const unsigned char* Dqq = Dq + ((size_t)q * NREC << 8);
    const float*         Iqq = Iq + ((size_t)q * NIN  << 8);

    const double rec_c = exp(-0.01 / (double)tau_rec[0]);
    const double out_c = exp(-0.01 / (double)tau_out[0]);
    const double thr   = (double)thr_rec[0];
    const double br    = (double)Br[q * SC + tid];
    double mem = 0.0, gacc = 0.0;
    double a0 = 0.0, a1 = 0.0, a2 = 0.0, a3 = 0.0;   // register delay ring

    const float* xb = x + (size_t)b * NIN * TT;
    float xv1 = xb[(size_t)tid * TT];                // input i = tid
    float xv2 = xb[(size_t)(tid + 256) * TT];        // input i = tid+256

    for (int t = 0; t < TT; ++t) {
        double cur = a0; a0 = a1; a1 = a2; a2 = a3; a3 = 0.0;

        // ---- input spike ballots (512 inputs over 256 threads, 2 each) ----
        const bool h1 = (xv1 != 0.f);
        const bool h2 = (xv2 != 0.f);
        const unsigned long long m1 = __ballot(h1);
        const unsigned long long m2 = __ballot(h2);
        if (lane == 0) { icnt[w] = __popcll(m1); icnt[4 + w] = __popcll(m2); }
        float x1n = 0.f, x2n = 0.f;
        if (t + 1 < TT) {
            x1n = xb[(size_t)tid * TT + (t + 1)];
            x2n = xb[(size_t)(tid + 256) * TT + (t + 1)];
        }
        __syncthreads();                               // B1: icnt ready
        int pre[9]; pre[0] = 0;
#pragma unroll
        for (int j = 0; j < 8; ++j) pre[j + 1] = pre[j] + icnt[j];
        const int itot = pre[8];
        if (h1) ilist[pre[w]     + lane_rank(m1)] = (unsigned short)tid;
        if (h2) ilist[pre[4 + w] + lane_rank(m2)] = (unsigned short)(tid + 256);
        __syncthreads();                               // B2: ilist ready

        // ---- input gather over my 256-col slice (unroll-4) ----
        {
            int k = 0;
            for (; k + 4 <= itot; k += 4) {
                const float v0 = Iqq[((size_t)ilist[k]     << 8) + tid];
                const float v1 = Iqq[((size_t)ilist[k + 1] << 8) + tid];
                const float v2 = Iqq[((size_t)ilist[k + 2] << 8) + tid];
                const float v3 = Iqq[((size_t)ilist[k + 3] << 8) + tid];
                cur += (double)v0; cur += (double)v1; cur += (double)v2; cur += (double)v3;
            }
            for (; k < itot; ++k) cur += (double)Iqq[((size_t)ilist[k] << 8) + tid];
        }
        cur += br;

        // ---- LIF + spike + soft reset + output Horner ----
        mem = mem * rec_c + cur;
        const bool z = (mem - thr) > 0.0;
        if (z) mem -= thr;
        gacc = gacc * out_c + (z ? 1.0 : 0.0);

        // ---- publish my 8 mask words directly from ballots; release ----
        const unsigned long long mz = __ballot(z);
        unsigned* gm = spikeMask + (size_t)(t * BB + b) * 64;
        if (lane == 0) {
            __hip_atomic_store(&gm[q * 8 + 2 * w],     (unsigned)(mz & 0xFFFFFFFFu),
                               __ATOMIC_RELAXED, __HIP_MEMORY_SCOPE_AGENT);
            __hip_atomic_store(&gm[q * 8 + 2 * w + 1], (unsigned)(mz >> 32),
                               __ATOMIC_RELAXED, __HIP_MEMORY_SCOPE_AGENT);
        }
        xv1 = x1n; xv2 = x2n;
        __syncthreads();                               // B3: vmcnt drained -> stores visible
        if (tid == 0) {
            __hip_atomic_fetch_add(&cnt[t * BB + b], 1u,
                                   __ATOMIC_RELEASE, __HIP_MEMORY_SCOPE_AGENT);
            if (t > 0) {                               // t=0 spikes never delivered
                while (__hip_atomic_load(&cnt[t * BB + b],
                                         __ATOMIC_ACQUIRE, __HIP_MEMORY_SCOPE_AGENT) < 8u)
                    __builtin_amdgcn_s_sleep(1);
            }
        }
        __syncthreads();                               // B4: all 8 siblings published

        if (t > 0) {
            // ---- read all 64 words, build slist (ascending, deterministic) ----
            if (tid < 64) {
                const unsigned wv = __hip_atomic_load(&gm[tid],
                                        __ATOMIC_RELAXED, __HIP_MEMORY_SCOPE_AGENT);
                words[tid] = wv;
                zcnt[tid]  = __popc(wv);
            }
            __syncthreads();                           // B5
            if (tid < 64) {
                int off = 0;
                for (int j = 0; j < tid; ++j) off += zcnt[j];
                zoff[tid] = off;
            }
            __syncthreads();                           // B6
            const int stot = zoff[63] + zcnt[63];
            if (tid < 64) {
                unsigned bits = words[tid];
                int off = zoff[tid];
                while (bits) {
                    const int bp = __ffs(bits) - 1;
                    bits &= bits - 1;
                    slist[off++] = (unsigned short)(tid * 32 + bp);
                }
            }
            __syncthreads();                           // B7: slist ready

            // ---- scatter into register ring (unroll-8, L2-resident rows) ----
            int k = 0;
            for (; k + 8 <= stot; k += 8) {
                size_t r0 = ((size_t)slist[k]     << 8) + tid;
                size_t r1 = ((size_t)slist[k + 1] << 8) + tid;
                size_t r2 = ((size_t)slist[k + 2] << 8) + tid;
                size_t r3 = ((size_t)slist[k + 3] << 8) + tid;
                size_t r4 = ((size_t)slist[k + 4] << 8) + tid;
                size_t r5 = ((size_t)slist[k + 5] << 8) + tid;
                size_t r6 = ((size_t)slist[k + 6] << 8) + tid;
                size_t r7 = ((size_t)slist[k + 7] << 8) + tid;
                const float w0 = Wqq[r0]; const int d0 = Dqq[r0];
                const float w1 = Wqq[r1]; const int d1 = Dqq[r1];
                const float w2 = Wqq[r2]; const int d2 = Dqq[r2];
                const float w3 = Wqq[r3]; const int d3 = Dqq[r3];
                const float w4 = Wqq[r4]; const int d4 = Dqq[r4];
                const float w5 = Wqq[r5]; const int d5 = Dqq[r5];
                const float w6 = Wqq[r6]; const int d6 = Dqq[r6];
                const float w7 = Wqq[r7]; const int d7 = Dqq[r7];
                a0 += (d0 == 1) ? (double)w0 : 0.0; a1 += (d0 == 2) ? (double)w0 : 0.0;
                a2 += (d0 == 3) ? (double)w0 : 0.0; a3 += (d0 == 4) ? (double)w0 : 0.0;
                a0 += (d1 == 1) ? (double)w1 : 0.0; a1 += (d1 == 2) ? (double)w1 : 0.0;
                a2 += (d1 == 3) ? (double)w1 : 0.0; a3 += (d1 == 4) ? (double)w1 : 0.0;
                a0 += (d2 == 1) ? (double)w2 : 0.0; a1 += (d2 == 2) ? (double)w2 : 0.0;
                a2 += (d2 == 3) ? (double)w2 : 0.0; a3 += (d2 == 4) ? (double)w2 : 0.0;
                a0 += (d3 == 1) ? (double)w3 : 0.0; a1 += (d3 == 2) ? (double)w3 : 0.0;
                a2 += (d3 == 3) ? (double)w3 : 0.0; a3 += (d3 == 4) ? (double)w3 : 0.0;
                a0 += (d4 == 1) ? (double)w4 : 0.0; a1 += (d4 == 2) ? (double)w4 : 0.0;
                a2 += (d4 == 3) ? (double)w4 : 0.0; a3 += (d4 == 4) ? (double)w4 : 0.0;
                a0 += (d5 == 1) ? (double)w5 : 0.0; a1 += (d5 == 2) ? (double)w5 : 0.0;
                a2 += (d5 == 3) ? (double)w5 : 0.0; a3 += (d5 == 4) ? (double)w5 : 0.0;
                a0 += (d6 == 1) ? (double)w6 : 0.0; a1 += (d6 == 2) ? (double)w6 : 0.0;
                a2 += (d6 == 3) ? (double)w6 : 0.0; a3 += (d6 == 4) ? (double)w6 : 0.0;
                a0 += (d7 == 1) ? (double)w7 : 0.0; a1 += (d7 == 2) ? (double)w7 : 0.0;
                a2 += (d7 == 3) ? (double)w7 : 0.0; a3 += (d7 == 4) ? (double)w7 : 0.0;
            }
            for (; k < stot; ++k) {
                const size_t r0 = ((size_t)slist[k] << 8) + tid;
                const float w0 = Wqq[r0]; const int d0 = Dqq[r0];
                a0 += (d0 == 1) ? (double)w0 : 0.0; a1 += (d0 == 2) ? (double)w0 : 0.0;
                a2 += (d0 == 3) ? (double)w0 : 0.0; a3 += (d0 == 4) ? (double)w0 : 0.0;
            }
        }
    }

    g[(size_t)b * NREC + q * SC + tid] = gacc;
}

__global__ __launch_bounds__(256) void k_memout(
    const double* __restrict__ g, const float* __restrict__ WoT,
    const float* __restrict__ Bo, const float* __restrict__ tau_out,
    float* __restrict__ mout)
{
    __shared__ double gs[NREC];
    const int b = blockIdx.x, tid = threadIdx.x;
#pragma unroll
    for (int k = 0; k < 8; ++k)
        gs[tid + 256 * k] = g[(size_t)b * NREC + tid + 256 * k];
    const double c = exp(-0.01 / (double)tau_out[0]);
    double S = 0.0;
    for (int t = 0; t < TT; ++t) S = S * c + 1.0;
    __syncthreads();
    if (tid < NOUT) {
        double a = 0.0;
        for (int n = 0; n < NREC; ++n)
            a += gs[n] * (double)WoT[n * NOUT + tid];
        a += (double)Bo[tid] * S;
        mout[(size_t)b * NOUT + tid] = (float)a;
    }
}

__global__ __launch_bounds__(256) void k_expand(
    const unsigned* __restrict__ spikeMask, float* __restrict__ zout)
{
    const int bid = blockIdx.x;
    const int b = bid >> 6, gw = bid & 63;
    const int t = threadIdx.x;
    if (t >= TT) return;
    const unsigned v = spikeMask[((size_t)(t * BB + b)) * 64 + gw];
    for (int j = 0; j < 32; ++j) {
        const int n = gw * 32 + j;
        zout[((size_t)b * NREC + n) * TT + t] = ((v >> j) & 1u) ? 1.0f : 0.0f;
    }
}

extern "C" void kernel_launch(void* const* d_in, const int* in_sizes, int n_in,
                              void* d_out, int out_size, void* d_ws, size_t ws_size,
                              hipStream_t stream) {
    const float *x = nullptr, *Wi = nullptr, *Wo = nullptr, *Br = nullptr, *Bo = nullptr;
    const void* c4[2] = {nullptr, nullptr};
    const float* sc[3] = {nullptr, nullptr, nullptr};
    int n4 = 0, nsc = 0;
    for (int i = 0; i < n_in; ++i) {
        switch (in_sizes[i]) {
            case 8192000: x  = (const float*)d_in[i]; break;
            case 1048576: Wi = (const float*)d_in[i]; break;
            case 262144:  Wo = (const float*)d_in[i]; break;
            case 2048:    Br = (const float*)d_in[i]; break;
            case 128:     Bo = (const float*)d_in[i]; break;
            case 4194304: if (n4 < 2)  c4[n4++]  = d_in[i]; break;
            case 1:       if (nsc < 3) sc[nsc++] = (const float*)d_in[i]; break;
            default: break;
        }
    }
    if (!x || !Wi || !Wo || !Br || !Bo || n4 < 2 || nsc < 3) {
        x  = (const float*)d_in[0];
        c4[0] = d_in[1];
        Wi = (const float*)d_in[2];
        c4[1] = d_in[3];
        Wo = (const float*)d_in[4];
        Br = (const float*)d_in[5];
        Bo = (const float*)d_in[6];
        sc[0] = (const float*)d_in[7];
        sc[1] = (const float*)d_in[8];
        sc[2] = (const float*)d_in[9];
    }
    const float* taur = sc[0];
    const float* tauo = sc[1];
    const float* thr  = sc[2];

    float* out = (float*)d_out;
    char* ws = (char*)d_ws;
    float*          Wq   = (float*)(ws + OFF_WQ);
    unsigned char*  Dq   = (unsigned char*)(ws + OFF_DQ);
    float*          Iq   = (float*)(ws + OFF_IQ);
    float*          WoT  = (float*)(ws + OFF_WOT);
    unsigned*       mask = (unsigned*)(ws + OFF_MASK);
    double*         g    = (double*)(ws + OFF_G);
    unsigned*       cnt  = (unsigned*)(ws + OFF_CNT);

    hipMemsetAsync(cnt, 0, (size_t)TT * BB * sizeof(unsigned), stream);
    hipLaunchKernelGGL(k_prep, dim3((NREC * NREC + 255) / 256), dim3(256), 0, stream,
                       c4[0], c4[1], Wi, Wo, Wq, Dq, Iq, WoT);
    hipLaunchKernelGGL(k_main, dim3(512), dim3(256), 0, stream,
                       x, Wq, Dq, Iq, Br, taur, tauo, thr, mask, cnt, g);
    hipLaunchKernelGGL(k_memout, dim3(BB), dim3(256), 0, stream,
                       g, WoT, Bo, tauo, out);
    hipLaunchKernelGGL(k_expand, dim3(BB * 64), dim3(256), 0, stream,
                       mask, out + 8192);
}

// Round 15
// 7066.310 us; speedup vs baseline: 1.1471x; 1.1471x over previous
//
#include <hip/hip_runtime.h>

#define NIN  512
#define NREC 2048
#define NOUT 128
#define BB   64
#define TT   250
#define NQ   8      // column slices; q self-assigned = hardware XCC_ID
#define SC   256    // columns per slice

// OUTPUTS FLOAT32 (R9). Semantics: JAX text (R10+ PASS, absmax 0.0078125).
// ---- d_ws layout (~31.4 MB; 34.5 MB verified safe) ----
#define OFF_WQ   0UL          // f32 [q][n][c] per-slice W_r^T   16,777,216
#define OFF_DQ   16777216UL   // u8  [q][n][c] per-slice delays   4,194,304
#define OFF_IQ   20971520UL   // f32 [q][i][c] per-slice W_i^T    4,194,304
#define OFF_WOT  25165824UL   // f32 [n][o] W_o^T                 1,048,576
#define OFF_MASK 26214400UL   // u32 masks [t*64+b][64]           4,096,000
#define OFF_G    30310400UL   // f64 g[b][n]                      1,048,576
#define OFF_CNT  31358976UL   // u32 cnt[TT*BB] + claim[16]          64,064 (memset 0)
#define CLAIMW   (TT * BB)    // word offset of claim area in cnt

__device__ __forceinline__ int decode_delay(int v) {
    if (v >= 0 && v <= 4) return v;
    const float f = __int_as_float(v);
    if (f >= 0.5f && f <= 4.5f) return (int)(f + 0.5f);
    return 0;
}
__device__ __forceinline__ int delay_like(int v) {
    if (v >= 0 && v <= 4) return 1;
    const float f = __int_as_float(v);
    return (f >= 0.5f && f <= 4.5f) ? 1 : 0;
}
__device__ __forceinline__ unsigned lane_rank(unsigned long long m) {
    unsigned r = __builtin_amdgcn_mbcnt_lo((unsigned)m, 0u);
    return __builtin_amdgcn_mbcnt_hi((unsigned)(m >> 32), r);
}

__global__ __launch_bounds__(256) void k_prep(
    const void* __restrict__ c4A, const void* __restrict__ c4B,
    const float* __restrict__ Wi, const float* __restrict__ Wo,
    float* __restrict__ Wq, unsigned char* __restrict__ Dq,
    float* __restrict__ Iq, float* __restrict__ WoT)
{
    const int* iA = (const int*)c4A;
    const int* iB = (const int*)c4B;
    int cntA = 0, cntB = 0;
    for (int j = 0; j < 64; ++j) { cntA += delay_like(iA[j]); cntB += delay_like(iB[j]); }
    const int*   dl = (cntA >= cntB) ? iA : iB;
    const float* Wr = (cntA >= cntB) ? (const float*)c4B : (const float*)c4A;

    const int idx = blockIdx.x * 256 + threadIdx.x;
    if (idx < NREC * NREC) {
        const int n = idx >> 11, m = idx & 2047;
        const int q = m >> 8, c = m & 255;
        const size_t dst = ((size_t)(q * NREC + n) << 8) + c;
        Wq[dst] = Wr[(size_t)m * NREC + n];              // W_r[m][n]
        Dq[dst] = (unsigned char)decode_delay(dl[idx]);  // delays[n][m]
    }
    if (idx < NIN * NREC) {
        const int i = idx >> 11, m = idx & 2047;
        const int q = m >> 8, c = m & 255;
        Iq[((size_t)(q * NIN + i) << 8) + c] = Wi[(size_t)m * NIN + i];   // W_i[m][i]
    }
    if (idx < NREC * NOUT) {
        const int n = idx >> 7, o = idx & 127;
        WoT[idx] = Wo[(size_t)o * NREC + n];
    }
}

// R15: 512 blocks x 256 threads. Block SELF-ASSIGNS q = its hardware XCC_ID
// (atomic slot claim; deterministic leftover assignment for overflow blocks),
// so slice q (2.625 MB) is resident in XCD q's 4 MB L2. 8-sibling per-step
// exchange via spikeMask + release/acquire counter; next-step input gather
// runs between release and acquire to hide sibling skew. All 512 blocks are
// resident by capacity (4 waves/block), so spins cannot deadlock.
__global__ __launch_bounds__(256) void k_main(
    const float* __restrict__ x,
    const float* __restrict__ Wq, const unsigned char* __restrict__ Dq,
    const float* __restrict__ Iq,
    const float* __restrict__ Br,
    const float* __restrict__ tau_rec, const float* __restrict__ tau_out,
    const float* __restrict__ thr_rec,
    unsigned* __restrict__ spikeMask, unsigned* __restrict__ cnt,
    double* __restrict__ g)
{
    __shared__ int icnt[8];
    __shared__ unsigned short ilist[NIN];
    __shared__ unsigned words[64];
    __shared__ int zcnt[64];
    __shared__ int zoff[64];
    __shared__ unsigned short slist[NREC];
    __shared__ int sQ, sB;

    const int tid  = threadIdx.x;
    const int w    = tid >> 6;         // wave 0..3
    const int lane = tid & 63;

    // ---- self-assignment: q = XCC_ID, b = claimed slot ----
    if (tid == 0) {
        unsigned xcc;
        asm volatile("s_getreg_b32 %0, hwreg(HW_REG_XCC_ID)" : "=s"(xcc));
        xcc &= 7u;
        const unsigned c = __hip_atomic_fetch_add(&cnt[CLAIMW + xcc], 1u,
                              __ATOMIC_RELAXED, __HIP_MEMORY_SCOPE_AGENT);
        unsigned ov = 0u;
        int q_ = (int)xcc, b_ = (int)c;
        if (c >= 64u)
            ov = __hip_atomic_fetch_add(&cnt[CLAIMW + 8], 1u,
                     __ATOMIC_RELAXED, __HIP_MEMORY_SCOPE_AGENT);
        __hip_atomic_fetch_add(&cnt[CLAIMW + 9], 1u,
                               __ATOMIC_RELEASE, __HIP_MEMORY_SCOPE_AGENT);
        if (c >= 64u) {
            while (__hip_atomic_load(&cnt[CLAIMW + 9],
                       __ATOMIC_ACQUIRE, __HIP_MEMORY_SCOPE_AGENT) < 512u)
                __builtin_amdgcn_s_sleep(2);
            unsigned rank = 0; q_ = -1;
            for (int qq = 0; qq < 8; ++qq) {
                const unsigned cl = __hip_atomic_load(&cnt[CLAIMW + qq],
                                        __ATOMIC_RELAXED, __HIP_MEMORY_SCOPE_AGENT);
                const unsigned st = (cl < 64u) ? cl : 64u;
                const unsigned nl = 64u - st;
                if (q_ < 0 && ov < rank + nl) { q_ = qq; b_ = (int)(st + (ov - rank)); }
                rank += nl;
            }
        }
        sQ = q_; sB = b_;
    }
    __syncthreads();
    const int q = sQ, b = sB;

    const float*         Wqq = Wq + ((size_t)q * NREC << 8);
    const unsigned char* Dqq = Dq + ((size_t)q * NREC << 8);
    const float*         Iqq = Iq + ((size_t)q * NIN  << 8);

    const double rec_c = exp(-0.01 / (double)tau_rec[0]);
    const double out_c = exp(-0.01 / (double)tau_out[0]);
    const double thr   = (double)thr_rec[0];
    const double br    = (double)Br[q * SC + tid];
    double mem = 0.0, gacc = 0.0;
    double a0 = 0.0, a1 = 0.0, a2 = 0.0, a3 = 0.0;   // register delay ring

    const float* xb = x + (size_t)b * NIN * TT;

    // ---- prologue: ilist/iacc for t=0 ----
    float xv1 = xb[(size_t)tid * TT];
    float xv2 = xb[(size_t)(tid + 256) * TT];
    double iacc;
    {
        const bool h1 = (xv1 != 0.f), h2 = (xv2 != 0.f);
        const unsigned long long m1 = __ballot(h1), m2 = __ballot(h2);
        if (lane == 0) { icnt[w] = __popcll(m1); icnt[4 + w] = __popcll(m2); }
        __syncthreads();
        int pre[9]; pre[0] = 0;
#pragma unroll
        for (int j = 0; j < 8; ++j) pre[j + 1] = pre[j] + icnt[j];
        const int itot = pre[8];
        if (h1) ilist[pre[w]     + lane_rank(m1)] = (unsigned short)tid;
        if (h2) ilist[pre[4 + w] + lane_rank(m2)] = (unsigned short)(tid + 256);
        __syncthreads();
        double s = br;
        for (int k = 0; k < itot; ++k) s += (double)Iqq[((size_t)ilist[k] << 8) + tid];
        iacc = s;
    }
    xv1 = (TT > 1) ? xb[(size_t)tid * TT + 1] : 0.f;
    xv2 = (TT > 1) ? xb[(size_t)(tid + 256) * TT + 1] : 0.f;

    for (int t = 0; t < TT; ++t) {
        // consume current scheduled for this step, rotate ring
        double cur = a0 + iacc; a0 = a1; a1 = a2; a2 = a3; a3 = 0.0;

        // ---- LIF + spike + soft reset + output Horner ----
        mem = mem * rec_c + cur;
        const bool z = (mem - thr) > 0.0;
        if (z) mem -= thr;
        gacc = gacc * out_c + (z ? 1.0 : 0.0);

        // ---- publish my 8 mask words; drain; release ----
        const unsigned long long mz = __ballot(z);
        unsigned* gm = spikeMask + (size_t)(t * BB + b) * 64;
        if (lane == 0) {
            __hip_atomic_store(&gm[q * 8 + 2 * w],     (unsigned)(mz & 0xFFFFFFFFu),
                               __ATOMIC_RELAXED, __HIP_MEMORY_SCOPE_AGENT);
            __hip_atomic_store(&gm[q * 8 + 2 * w + 1], (unsigned)(mz >> 32),
                               __ATOMIC_RELAXED, __HIP_MEMORY_SCOPE_AGENT);
        }
        __syncthreads();                               // B3: stores drained
        if (tid == 0)
            __hip_atomic_fetch_add(&cnt[t * BB + b], 1u,
                                   __ATOMIC_RELEASE, __HIP_MEMORY_SCOPE_AGENT);

        // ---- hidden work: build ilist(t+1) + gather iaccN while siblings run ----
        const bool h1 = (xv1 != 0.f), h2 = (xv2 != 0.f);
        const unsigned long long m1 = __ballot(h1), m2 = __ballot(h2);
        if (lane == 0) { icnt[w] = __popcll(m1); icnt[4 + w] = __popcll(m2); }
        __syncthreads();                               // B1
        int pre[9]; pre[0] = 0;
#pragma unroll
        for (int j = 0; j < 8; ++j) pre[j + 1] = pre[j] + icnt[j];
        const int itot = pre[8];
        if (h1) ilist[pre[w]     + lane_rank(m1)] = (unsigned short)tid;
        if (h2) ilist[pre[4 + w] + lane_rank(m2)] = (unsigned short)(tid + 256);
        __syncthreads();                               // B2
        double iaccN = br;
        {
            int k = 0;
            for (; k + 4 <= itot; k += 4) {
                const float v0 = Iqq[((size_t)ilist[k]     << 8) + tid];
                const float v1 = Iqq[((size_t)ilist[k + 1] << 8) + tid];
                const float v2 = Iqq[((size_t)ilist[k + 2] << 8) + tid];
                const float v3 = Iqq[((size_t)ilist[k + 3] << 8) + tid];
                iaccN += (double)v0; iaccN += (double)v1;
                iaccN += (double)v2; iaccN += (double)v3;
            }
            for (; k < itot; ++k) iaccN += (double)Iqq[((size_t)ilist[k] << 8) + tid];
        }
        if (t + 2 < TT) {
            xv1 = xb[(size_t)tid * TT + (t + 2)];
            xv2 = xb[(size_t)(tid + 256) * TT + (t + 2)];
        } else { xv1 = 0.f; xv2 = 0.f; }

        // ---- acquire all 8 siblings; scatter their spikes (t>0 gate) ----
        if (t > 0) {
            if (tid == 0) {
                while (__hip_atomic_load(&cnt[t * BB + b],
                           __ATOMIC_ACQUIRE, __HIP_MEMORY_SCOPE_AGENT) < 8u)
                    __builtin_amdgcn_s_sleep(1);
            }
            __syncthreads();                           // B4: all 8 published
            if (tid < 64) {
                const unsigned wv = __hip_atomic_load(&gm[tid],
                                        __ATOMIC_RELAXED, __HIP_MEMORY_SCOPE_AGENT);
                words[tid] = wv;
                zcnt[tid]  = __popc(wv);
            }
            __syncthreads();                           // B5
            if (tid < 64) {
                int off = 0;
                for (int j = 0; j < tid; ++j) off += zcnt[j];
                zoff[tid] = off;
            }
            __syncthreads();                           // B6
            const int stot = zoff[63] + zcnt[63];
            if (tid < 64) {
                unsigned bits = words[tid];
                int off = zoff[tid];
                while (bits) {
                    const int bp = __ffs(bits) - 1;
                    bits &= bits - 1;
                    slist[off++] = (unsigned short)(tid * 32 + bp);
                }
            }
            __syncthreads();                           // B7: slist ready

            int k = 0;
            for (; k + 8 <= stot; k += 8) {
                const size_t r0 = ((size_t)slist[k]     << 8) + tid;
                const size_t r1 = ((size_t)slist[k + 1] << 8) + tid;
                const size_t r2 = ((size_t)slist[k + 2] << 8) + tid;
                const size_t r3 = ((size_t)slist[k + 3] << 8) + tid;
                const size_t r4 = ((size_t)slist[k + 4] << 8) + tid;
                const size_t r5 = ((size_t)slist[k + 5] << 8) + tid;
                const size_t r6 = ((size_t)slist[k + 6] << 8) + tid;
                const size_t r7 = ((size_t)slist[k + 7] << 8) + tid;
                const float w0 = Wqq[r0]; const int d0 = Dqq[r0];
                const float w1 = Wqq[r1]; const int d1 = Dqq[r1];
                const float w2 = Wqq[r2]; const int d2 = Dqq[r2];
                const float w3 = Wqq[r3]; const int d3 = Dqq[r3];
                const float w4 = Wqq[r4]; const int d4 = Dqq[r4];
                const float w5 = Wqq[r5]; const int d5 = Dqq[r5];
                const float w6 = Wqq[r6]; const int d6 = Dqq[r6];
                const float w7 = Wqq[r7]; const int d7 = Dqq[r7];
                a0 += (d0 == 1) ? (double)w0 : 0.0; a1 += (d0 == 2) ? (double)w0 : 0.0;
                a2 += (d0 == 3) ? (double)w0 : 0.0; a3 += (d0 == 4) ? (double)w0 : 0.0;
                a0 += (d1 == 1) ? (double)w1 : 0.0; a1 += (d1 == 2) ? (double)w1 : 0.0;
                a2 += (d1 == 3) ? (double)w1 : 0.0; a3 += (d1 == 4) ? (double)w1 : 0.0;
                a0 += (d2 == 1) ? (double)w2 : 0.0; a1 += (d2 == 2) ? (double)w2 : 0.0;
                a2 += (d2 == 3) ? (double)w2 : 0.0; a3 += (d2 == 4) ? (double)w2 : 0.0;
                a0 += (d3 == 1) ? (double)w3 : 0.0; a1 += (d3 == 2) ? (double)w3 : 0.0;
                a2 += (d3 == 3) ? (double)w3 : 0.0; a3 += (d3 == 4) ? (double)w3 : 0.0;
                a0 += (d4 == 1) ? (double)w4 : 0.0; a1 += (d4 == 2) ? (double)w4 : 0.0;
                a2 += (d4 == 3) ? (double)w4 : 0.0; a3 += (d4 == 4) ? (double)w4 : 0.0;
                a0 += (d5 == 1) ? (double)w5 : 0.0; a1 += (d5 == 2) ? (double)w5 : 0.0;
                a2 += (d5 == 3) ? (double)w5 : 0.0; a3 += (d5 == 4) ? (double)w5 : 0.0;
                a0 += (d6 == 1) ? (double)w6 : 0.0; a1 += (d6 == 2) ? (double)w6 : 0.0;
                a2 += (d6 == 3) ? (double)w6 : 0.0; a3 += (d6 == 4) ? (double)w6 : 0.0;
                a0 += (d7 == 1) ? (double)w7 : 0.0; a1 += (d7 == 2) ? (double)w7 : 0.0;
                a2 += (d7 == 3) ? (double)w7 : 0.0; a3 += (d7 == 4) ? (double)w7 : 0.0;
            }
            for (; k < stot; ++k) {
                const size_t r0 = ((size_t)slist[k] << 8) + tid;
                const float w0 = Wqq[r0]; const int d0 = Dqq[r0];
                a0 += (d0 == 1) ? (double)w0 : 0.0; a1 += (d0 == 2) ? (double)w0 : 0.0;
                a2 += (d0 == 3) ? (double)w0 : 0.0; a3 += (d0 == 4) ? (double)w0 : 0.0;
            }
        }
        iacc = iaccN;
    }

    g[(size_t)b * NREC + q * SC + tid] = gacc;
}

__global__ __launch_bounds__(256) void k_memout(
    const double* __restrict__ g, const float* __restrict__ WoT,
    const float* __restrict__ Bo, const float* __restrict__ tau_out,
    float* __restrict__ mout)
{
    __shared__ double gs[NREC];
    const int b = blockIdx.x, tid = threadIdx.x;
#pragma unroll
    for (int k = 0; k < 8; ++k)
        gs[tid + 256 * k] = g[(size_t)b * NREC + tid + 256 * k];
    const double c = exp(-0.01 / (double)tau_out[0]);
    double S = 0.0;
    for (int t = 0; t < TT; ++t) S = S * c + 1.0;
    __syncthreads();
    if (tid < NOUT) {
        double a = 0.0;
        for (int n = 0; n < NREC; ++n)
            a += gs[n] * (double)WoT[n * NOUT + tid];
        a += (double)Bo[tid] * S;
        mout[(size_t)b * NOUT + tid] = (float)a;
    }
}

__global__ __launch_bounds__(256) void k_expand(
    const unsigned* __restrict__ spikeMask, float* __restrict__ zout)
{
    const int bid = blockIdx.x;
    const int b = bid >> 6, gw = bid & 63;
    const int t = threadIdx.x;
    if (t >= TT) return;
    const unsigned v = spikeMask[((size_t)(t * BB + b)) * 64 + gw];
    for (int j = 0; j < 32; ++j) {
        const int n = gw * 32 + j;
        zout[((size_t)b * NREC + n) * TT + t] = ((v >> j) & 1u) ? 1.0f : 0.0f;
    }
}

extern "C" void kernel_launch(void* const* d_in, const int* in_sizes, int n_in,
                              void* d_out, int out_size, void* d_ws, size_t ws_size,
                              hipStream_t stream) {
    const float *x = nullptr, *Wi = nullptr, *Wo = nullptr, *Br = nullptr, *Bo = nullptr;
    const void* c4[2] = {nullptr, nullptr};
    const float* sc[3] = {nullptr, nullptr, nullptr};
    int n4 = 0, nsc = 0;
    for (int i = 0; i < n_in; ++i) {
        switch (in_sizes[i]) {
            case 8192000: x  = (const float*)d_in[i]; break;
            case 1048576: Wi = (const float*)d_in[i]; break;
            case 262144:  Wo = (const float*)d_in[i]; break;
            case 2048:    Br = (const float*)d_in[i]; break;
            case 128:     Bo = (const float*)d_in[i]; break;
            case 4194304: if (n4 < 2)  c4[n4++]  = d_in[i]; break;
            case 1:       if (nsc < 3) sc[nsc++] = (const float*)d_in[i]; break;
            default: break;
        }
    }
    if (!x || !Wi || !Wo || !Br || !Bo || n4 < 2 || nsc < 3) {
        x  = (const float*)d_in[0];
        c4[0] = d_in[1];
        Wi = (const float*)d_in[2];
        c4[1] = d_in[3];
        Wo = (const float*)d_in[4];
        Br = (const float*)d_in[5];
        Bo = (const float*)d_in[6];
        sc[0] = (const float*)d_in[7];
        sc[1] = (const float*)d_in[8];
        sc[2] = (const float*)d_in[9];
    }
    const float* taur = sc[0];
    const float* tauo = sc[1];
    const float* thr  = sc[2];

    float* out = (float*)d_out;
    char* ws = (char*)d_ws;
    float*          Wq   = (float*)(ws + OFF_WQ);
    unsigned char*  Dq   = (unsigned char*)(ws + OFF_DQ);
    float*          Iq   = (float*)(ws + OFF_IQ);
    float*          WoT  = (float*)(ws + OFF_WOT);
    unsigned*       mask = (unsigned*)(ws + OFF_MASK);
    double*         g    = (double*)(ws + OFF_G);
    unsigned*       cnt  = (unsigned*)(ws + OFF_CNT);

    hipMemsetAsync(cnt, 0, (size_t)(CLAIMW + 16) * sizeof(unsigned), stream);
    hipLaunchKernelGGL(k_prep, dim3((NREC * NREC + 255) / 256), dim3(256), 0, stream,
                       c4[0], c4[1], Wi, Wo, Wq, Dq, Iq, WoT);
    hipLaunchKernelGGL(k_main, dim3(512), dim3(256), 0, stream,
                       x, Wq, Dq, Iq, Br, taur, tauo, thr, mask, cnt, g);
    hipLaunchKernelGGL(k_memout, dim3(BB), dim3(256), 0, stream,
                       g, WoT, Bo, tauo, out);
    hipLaunchKernelGGL(k_expand, dim3(BB * 64), dim3(256), 0, stream,
                       mask, out + 8192);
}